// Round 1
// baseline (946.724 us; speedup 1.0000x reference)
//
#include <hip/hip_runtime.h>
#include <hip/hip_bf16.h>
#include <cstdint>

#define D_MODEL 1024
#define NHEADS 16
#define DHEAD 64
#define DMLP 4096
#define BATCH 2
#define SEQ 2048
#define ROWS (BATCH*SEQ)
#define LN_EPS 1e-5f

typedef __attribute__((ext_vector_type(8))) short short8;
typedef __attribute__((ext_vector_type(4))) float f32x4;

typedef const __attribute__((address_space(1))) uint32_t* gas_ptr;
typedef __attribute__((address_space(3))) uint32_t* las_ptr;

__device__ __forceinline__ short f2bf(float f) {
  union { float f; uint32_t u; } v; v.f = f;
  uint32_t r = v.u + 0x7FFFu + ((v.u >> 16) & 1u);
  return (short)(r >> 16);
}
__device__ __forceinline__ float bf2f(short s) {
  union { uint32_t u; float f; } v; v.u = ((uint32_t)(uint16_t)s) << 16;
  return v.f;
}

// ---------------- LayerNorm: one block per row, 256 threads, D=1024 ----------------
__global__ void ln_kernel(const float* __restrict__ x, const float* __restrict__ w,
                          const float* __restrict__ b, short* __restrict__ out) {
  int row = blockIdx.x;
  int t = threadIdx.x;
  const float4 v = ((const float4*)(x + (size_t)row * D_MODEL))[t];
  float s = v.x + v.y + v.z + v.w;
  float s2 = v.x*v.x + v.y*v.y + v.z*v.z + v.w*v.w;
#pragma unroll
  for (int k = 1; k < 64; k <<= 1) { s += __shfl_xor(s, k); s2 += __shfl_xor(s2, k); }
  __shared__ float red[8];
  int wv = t >> 6;
  if ((t & 63) == 0) { red[wv] = s; red[wv + 4] = s2; }
  __syncthreads();
  s = red[0] + red[1] + red[2] + red[3];
  s2 = red[4] + red[5] + red[6] + red[7];
  float mu = s * (1.0f / D_MODEL);
  float var = s2 * (1.0f / D_MODEL) - mu * mu;
  float rstd = rsqrtf(var + LN_EPS);
  const float4 wv4 = ((const float4*)w)[t];
  const float4 bv4 = ((const float4*)b)[t];
  short4 o4;
  o4.x = f2bf((v.x - mu) * rstd * wv4.x + bv4.x);
  o4.y = f2bf((v.y - mu) * rstd * wv4.y + bv4.y);
  o4.z = f2bf((v.z - mu) * rstd * wv4.z + bv4.z);
  o4.w = f2bf((v.w - mu) * rstd * wv4.w + bv4.w);
  *(short4*)(out + (size_t)row * D_MODEL + t * 4) = o4;
}

// ---------------- Weight repack: WQ/WK/WV -> bf16 B^T [3072][1024] ----------------
__global__ void repack_qkv(const float* __restrict__ WQ, const float* __restrict__ WK,
                           const float* __restrict__ WV, short* __restrict__ out) {
  int id = blockIdx.x * 256 + threadIdx.x;     // over 3072*1024
  int d = id & 1023;           // k index
  int n = id >> 10;            // output col 0..3071
  int proj = n >> 10;
  int he = n & 1023;
  int h = he >> 6, e = he & 63;
  const float* W = (proj == 0) ? WQ : ((proj == 1) ? WK : WV);
  out[id] = f2bf(W[h * (D_MODEL * DHEAD) + d * DHEAD + e]);
}

// generic transpose+convert: src[R][C] f32 -> dst[C][R] bf16   (C = 1<<Cbits)
__global__ void transpose_cvt(const float* __restrict__ src, short* __restrict__ dst,
                              int R, int Cbits) {
  int id = blockIdx.x * 256 + threadIdx.x;
  int r = id >> Cbits;
  int c = id & ((1 << Cbits) - 1);
  dst[(size_t)c * R + r] = f2bf(src[id]);
}

// ---------------- bf16 MFMA GEMM, 128x128 tile, BK=32, B^T input ----------------
// EPI 0: bf16 store (outb)          EPI 1: f32 store + resid (outf)
// EPI 2: bias+GELU -> bf16 (outb)   EPI 3: bias + resid -> f32 (outf)
template<int EPI>
__global__ __launch_bounds__(256) void gemm_bt(const short* __restrict__ A, const short* __restrict__ BT,
                        const float* __restrict__ bias, const float* __restrict__ resid,
                        float* __restrict__ outf, short* __restrict__ outb,
                        int M, int N, int K) {
  __shared__ alignas(16) short As[128 * 32];
  __shared__ alignas(16) short Bs[128 * 32];
  const int t = threadIdx.x;
  const int l = t & 63;
  const int w = t >> 6;
  const int row0 = blockIdx.y * 128, col0 = blockIdx.x * 128;

  f32x4 acc[4][4] = {};

  const int srow = w * 16 + (l >> 2);          // 0..63
  const int schunk = (l & 3) * 8;              // k offset in elements
  const short* Abase = A + (size_t)(row0 + srow) * K + schunk;
  const short* Bbase = BT + (size_t)(col0 + srow) * K + schunk;
  char* AsB = (char*)As;
  char* BsB = (char*)Bs;
  const int ldsoff = w * 1024 + l * 16;        // bytes, linear per wave

  const int wr = (w >> 1) * 64, wc = (w & 1) * 64;
  const int lk = (l >> 4) * 8;
  const int lr16 = l & 15;

  for (int k0 = 0; k0 < K; k0 += 32) {
    __builtin_amdgcn_global_load_lds((gas_ptr)(Abase + k0),          (las_ptr)(AsB + ldsoff),        16, 0, 0);
    __builtin_amdgcn_global_load_lds((gas_ptr)(Abase + 64 * K + k0), (las_ptr)(AsB + 4096 + ldsoff), 16, 0, 0);
    __builtin_amdgcn_global_load_lds((gas_ptr)(Bbase + k0),          (las_ptr)(BsB + ldsoff),        16, 0, 0);
    __builtin_amdgcn_global_load_lds((gas_ptr)(Bbase + 64 * K + k0), (las_ptr)(BsB + 4096 + ldsoff), 16, 0, 0);
    __syncthreads();

    short8 a[4], bfr[4];
#pragma unroll
    for (int m = 0; m < 4; m++) a[m]   = *(const short8*)&As[(wr + m * 16 + lr16) * 32 + lk];
#pragma unroll
    for (int n = 0; n < 4; n++) bfr[n] = *(const short8*)&Bs[(wc + n * 16 + lr16) * 32 + lk];
#pragma unroll
    for (int m = 0; m < 4; m++)
#pragma unroll
      for (int n = 0; n < 4; n++)
        acc[m][n] = __builtin_amdgcn_mfma_f32_16x16x32_bf16(a[m], bfr[n], acc[m][n], 0, 0, 0);
    __syncthreads();
  }

  // epilogue: D[row][col], row=(l>>4)*4+j, col=l&15 within each 16x16 fragment
#pragma unroll
  for (int m = 0; m < 4; m++) {
#pragma unroll
    for (int n = 0; n < 4; n++) {
#pragma unroll
      for (int j = 0; j < 4; j++) {
        int R_ = row0 + wr + m * 16 + (l >> 4) * 4 + j;
        int C_ = col0 + wc + n * 16 + lr16;
        float v = acc[m][n][j];
        size_t o = (size_t)R_ * N + C_;
        if (EPI == 0) {
          outb[o] = f2bf(v);
        } else if (EPI == 1) {
          outf[o] = v + resid[o];
        } else if (EPI == 2) {
          float xx = v + bias[C_];
          outb[o] = f2bf(0.5f * xx * (1.0f + erff(xx * 0.70710678118f)));
        } else {
          outf[o] = v + bias[C_] + resid[o];
        }
      }
    }
  }
}

// ---------------- fp32 flash-style attention: QB=32, KB=32, 256 threads ----------------
__global__ __launch_bounds__(256) void attn_kernel(const short* __restrict__ qkv, short* __restrict__ ctx) {
  __shared__ alignas(16) float Ks[32][68];
  __shared__ alignas(16) float Vs[32][68];
  __shared__ float Ps[32][33];
  const int t = threadIdx.x;
  const int bh = blockIdx.y;
  const int b = bh >> 4, h = bh & 15;
  const int qt = blockIdx.x;
  const int q0 = qt * 32;
  const int r = t >> 3;       // q-row (and k/v-row for loads) in tile
  const int dg = t & 7;       // dim-group / key-subgroup
  const int lc = dg * 8;

  // Q row into registers (fp32)
  float q[64];
  {
    const short* qp = qkv + ((size_t)(b * SEQ + q0 + r)) * 3072 + h * 64;
#pragma unroll
    for (int i = 0; i < 8; i++) {
      short8 qq = *(const short8*)(qp + i * 8);
#pragma unroll
      for (int j = 0; j < 8; j++) q[i * 8 + j] = bf2f(qq[j]);
    }
  }
  float m_run = -1e30f, l_run = 0.0f;
  float acc[8] = {0, 0, 0, 0, 0, 0, 0, 0};
  const int nkt = qt + 1;
  for (int kt = 0; kt < nkt; kt++) {
    __syncthreads();   // protect K/V/P from previous iteration's readers
    {
      const short* kb = qkv + ((size_t)(b * SEQ + kt * 32 + r)) * 3072 + 1024 + h * 64 + lc;
      short8 k8 = *(const short8*)kb;
      short8 v8 = *(const short8*)(kb + 1024);
#pragma unroll
      for (int i = 0; i < 8; i++) { Ks[r][lc + i] = bf2f(k8[i]); Vs[r][lc + i] = bf2f(v8[i]); }
    }
    __syncthreads();
    float sc[4];
#pragma unroll
    for (int jj = 0; jj < 4; jj++) {
      int j = dg + jj * 8;
      float s = 0.0f;
#pragma unroll
      for (int e = 0; e < 64; e += 4) {
        float4 kk = *(const float4*)&Ks[j][e];
        s += q[e] * kk.x + q[e + 1] * kk.y + q[e + 2] * kk.z + q[e + 3] * kk.w;
      }
      s *= 0.125f;                      // 1/sqrt(64)
      if (kt * 32 + j > q0 + r) s = -1e30f;   // causal mask
      sc[jj] = s;
    }
    float tm = fmaxf(fmaxf(sc[0], sc[1]), fmaxf(sc[2], sc[3]));
#pragma unroll
    for (int k = 1; k < 8; k <<= 1) tm = fmaxf(tm, __shfl_xor(tm, k));
    float newm = fmaxf(m_run, tm);
    float alpha = __expf(m_run - newm);
    float psum = 0.0f;
#pragma unroll
    for (int jj = 0; jj < 4; jj++) {
      float pv = __expf(sc[jj] - newm);
      Ps[r][dg + jj * 8] = pv;
      psum += pv;
    }
#pragma unroll
    for (int k = 1; k < 8; k <<= 1) psum += __shfl_xor(psum, k);
    l_run = alpha * l_run + psum;
    m_run = newm;
    __syncthreads();
#pragma unroll
    for (int dd = 0; dd < 8; dd++) acc[dd] *= alpha;
#pragma unroll
    for (int j = 0; j < 32; j++) {
      float pv = Ps[r][j];
      const float4 v0 = *(const float4*)&Vs[j][dg * 8];
      const float4 v1 = *(const float4*)&Vs[j][dg * 8 + 4];
      acc[0] += pv * v0.x; acc[1] += pv * v0.y; acc[2] += pv * v0.z; acc[3] += pv * v0.w;
      acc[4] += pv * v1.x; acc[5] += pv * v1.y; acc[6] += pv * v1.z; acc[7] += pv * v1.w;
    }
  }
  float inv = 1.0f / l_run;
  short8 o8;
#pragma unroll
  for (int dd = 0; dd < 8; dd++) o8[dd] = f2bf(acc[dd] * inv);
  *(short8*)&ctx[((size_t)(b * SEQ + q0 + r)) * D_MODEL + h * 64 + dg * 8] = o8;
}

extern "C" void kernel_launch(void* const* d_in, const int* in_sizes, int n_in,
                              void* d_out, int out_size, void* d_ws, size_t ws_size,
                              hipStream_t stream) {
  (void)in_sizes; (void)n_in; (void)out_size; (void)ws_size;
  const float* x    = (const float*)d_in[0];
  const float* WQ   = (const float*)d_in[1];
  const float* WK   = (const float*)d_in[2];
  const float* WV   = (const float*)d_in[3];
  const float* WO   = (const float*)d_in[4];
  const float* W1   = (const float*)d_in[5];
  const float* b1   = (const float*)d_in[6];
  const float* W2   = (const float*)d_in[7];
  const float* b2   = (const float*)d_in[8];
  const float* ln1w = (const float*)d_in[9];
  const float* ln1b = (const float*)d_in[10];
  const float* ln2w = (const float*)d_in[11];
  const float* ln2b = (const float*)d_in[12];
  float* out = (float*)d_out;

  char* p = (char*)d_ws;
  short* h1    = (short*)p; p += (size_t)ROWS * D_MODEL * 2;        // 8 MB
  short* ctx   = (short*)p; p += (size_t)ROWS * D_MODEL * 2;        // 8 MB
  short* h2    = (short*)p; p += (size_t)ROWS * D_MODEL * 2;        // 8 MB
  short* m1    = (short*)p; p += (size_t)ROWS * DMLP * 2;           // 32 MB
  short* wqkvT = (short*)p; p += (size_t)3 * D_MODEL * D_MODEL * 2; // 6 MB
  short* woT   = (short*)p; p += (size_t)D_MODEL * D_MODEL * 2;     // 2 MB
  short* w1T   = (short*)p; p += (size_t)D_MODEL * DMLP * 2;        // 8 MB
  short* w2T   = (short*)p; p += (size_t)D_MODEL * DMLP * 2;        // 8 MB
  short* qkv   = (short*)p; p += (size_t)ROWS * 3 * D_MODEL * 2;    // 24 MB

  // weight repacks (bf16, B^T layout)
  repack_qkv<<<3 * D_MODEL * D_MODEL / 256, 256, 0, stream>>>(WQ, WK, WV, wqkvT);
  transpose_cvt<<<D_MODEL * D_MODEL / 256, 256, 0, stream>>>(WO, woT, D_MODEL, 10);
  transpose_cvt<<<D_MODEL * DMLP / 256, 256, 0, stream>>>(W1, w1T, D_MODEL, 12);
  transpose_cvt<<<D_MODEL * DMLP / 256, 256, 0, stream>>>(W2, w2T, DMLP, 10);

  // LN1
  ln_kernel<<<ROWS, 256, 0, stream>>>(x, ln1w, ln1b, h1);
  // QKV projection: [4096,1024] x [1024,3072] -> bf16 qkv
  gemm_bt<0><<<dim3(3 * D_MODEL / 128, ROWS / 128), 256, 0, stream>>>(
      h1, wqkvT, nullptr, nullptr, nullptr, qkv, ROWS, 3 * D_MODEL, D_MODEL);
  // attention
  attn_kernel<<<dim3(SEQ / 32, BATCH * NHEADS), 256, 0, stream>>>(qkv, ctx);
  // output projection + residual -> x1 (d_out, f32)
  gemm_bt<1><<<dim3(D_MODEL / 128, ROWS / 128), 256, 0, stream>>>(
      ctx, woT, nullptr, x, out, nullptr, ROWS, D_MODEL, D_MODEL);
  // LN2
  ln_kernel<<<ROWS, 256, 0, stream>>>(out, ln2w, ln2b, h2);
  // MLP fc1 + GELU -> bf16 m1
  gemm_bt<2><<<dim3(DMLP / 128, ROWS / 128), 256, 0, stream>>>(
      h2, w1T, b1, nullptr, nullptr, m1, ROWS, DMLP, D_MODEL);
  // MLP fc2 + bias + residual -> d_out (f32)
  gemm_bt<3><<<dim3(D_MODEL / 128, ROWS / 128), 256, 0, stream>>>(
      m1, w2T, b2, out, out, nullptr, ROWS, D_MODEL, DMLP);
}

// Round 2
// 419.752 us; speedup vs baseline: 2.2554x; 2.2554x over previous
//
#include <hip/hip_runtime.h>
#include <hip/hip_bf16.h>
#include <cstdint>

#define D_MODEL 1024
#define NHEADS 16
#define DHEAD 64
#define DMLP 4096
#define BATCH 2
#define SEQ 2048
#define ROWS (BATCH*SEQ)
#define LN_EPS 1e-5f

typedef __attribute__((ext_vector_type(8))) short short8;
typedef __attribute__((ext_vector_type(4))) float f32x4;

typedef const __attribute__((address_space(1))) uint32_t* gas_ptr;
typedef __attribute__((address_space(3))) uint32_t* las_ptr;

__device__ __forceinline__ short f2bf(float f) {
  union { float f; uint32_t u; } v; v.f = f;
  uint32_t r = v.u + 0x7FFFu + ((v.u >> 16) & 1u);
  return (short)(r >> 16);
}
__device__ __forceinline__ float bf2f(short s) {
  union { uint32_t u; float f; } v; v.u = ((uint32_t)(uint16_t)s) << 16;
  return v.f;
}

// ---------------- LayerNorm: one block per row, 256 threads, D=1024 ----------------
__global__ void ln_kernel(const float* __restrict__ x, const float* __restrict__ w,
                          const float* __restrict__ b, short* __restrict__ out) {
  int row = blockIdx.x;
  int t = threadIdx.x;
  const float4 v = ((const float4*)(x + (size_t)row * D_MODEL))[t];
  float s = v.x + v.y + v.z + v.w;
  float s2 = v.x*v.x + v.y*v.y + v.z*v.z + v.w*v.w;
#pragma unroll
  for (int k = 1; k < 64; k <<= 1) { s += __shfl_xor(s, k); s2 += __shfl_xor(s2, k); }
  __shared__ float red[8];
  int wv = t >> 6;
  if ((t & 63) == 0) { red[wv] = s; red[wv + 4] = s2; }
  __syncthreads();
  s = red[0] + red[1] + red[2] + red[3];
  s2 = red[4] + red[5] + red[6] + red[7];
  float mu = s * (1.0f / D_MODEL);
  float var = s2 * (1.0f / D_MODEL) - mu * mu;
  float rstd = rsqrtf(var + LN_EPS);
  const float4 wv4 = ((const float4*)w)[t];
  const float4 bv4 = ((const float4*)b)[t];
  short4 o4;
  o4.x = f2bf((v.x - mu) * rstd * wv4.x + bv4.x);
  o4.y = f2bf((v.y - mu) * rstd * wv4.y + bv4.y);
  o4.z = f2bf((v.z - mu) * rstd * wv4.z + bv4.z);
  o4.w = f2bf((v.w - mu) * rstd * wv4.w + bv4.w);
  *(short4*)(out + (size_t)row * D_MODEL + t * 4) = o4;
}

// ---------------- Weight repack: WQ/WK/WV -> bf16 B^T [3072][1024] ----------------
__global__ void repack_qkv(const float* __restrict__ WQ, const float* __restrict__ WK,
                           const float* __restrict__ WV, short* __restrict__ out) {
  int id = blockIdx.x * 256 + threadIdx.x;     // over 3072*1024
  int d = id & 1023;           // k index
  int n = id >> 10;            // output col 0..3071
  int proj = n >> 10;
  int he = n & 1023;
  int h = he >> 6, e = he & 63;
  const float* W = (proj == 0) ? WQ : ((proj == 1) ? WK : WV);
  out[id] = f2bf(W[h * (D_MODEL * DHEAD) + d * DHEAD + e]);
}

// generic transpose+convert: src[R][C] f32 -> dst[C][R] bf16   (C = 1<<Cbits)
__global__ void transpose_cvt(const float* __restrict__ src, short* __restrict__ dst,
                              int R, int Cbits) {
  int id = blockIdx.x * 256 + threadIdx.x;
  int r = id >> Cbits;
  int c = id & ((1 << Cbits) - 1);
  dst[(size_t)c * R + r] = f2bf(src[id]);
}

// ---------------- bf16 MFMA GEMM, 128x128 tile, BK=32, B^T input ----------------
// EPI 0: bf16 store (outb)          EPI 1: f32 store + resid (outf)
// EPI 2: bias+GELU -> bf16 (outb)   EPI 3: bias + resid -> f32 (outf)
template<int EPI>
__global__ __launch_bounds__(256) void gemm_bt(const short* __restrict__ A, const short* __restrict__ BT,
                        const float* __restrict__ bias, const float* __restrict__ resid,
                        float* __restrict__ outf, short* __restrict__ outb,
                        int M, int N, int K) {
  __shared__ alignas(16) short As[128 * 32];
  __shared__ alignas(16) short Bs[128 * 32];
  const int t = threadIdx.x;
  const int l = t & 63;
  const int w = t >> 6;
  const int row0 = blockIdx.y * 128, col0 = blockIdx.x * 128;

  f32x4 acc[4][4] = {};

  const int srow = w * 16 + (l >> 2);          // 0..63
  const int schunk = (l & 3) * 8;              // k offset in elements
  const short* Abase = A + (size_t)(row0 + srow) * K + schunk;
  const short* Bbase = BT + (size_t)(col0 + srow) * K + schunk;
  char* AsB = (char*)As;
  char* BsB = (char*)Bs;
  const int ldsoff = w * 1024 + l * 16;        // bytes, linear per wave

  const int wr = (w >> 1) * 64, wc = (w & 1) * 64;
  const int lk = (l >> 4) * 8;
  const int lr16 = l & 15;

  for (int k0 = 0; k0 < K; k0 += 32) {
    __builtin_amdgcn_global_load_lds((gas_ptr)(Abase + k0),          (las_ptr)(AsB + ldsoff),        16, 0, 0);
    __builtin_amdgcn_global_load_lds((gas_ptr)(Abase + 64 * K + k0), (las_ptr)(AsB + 4096 + ldsoff), 16, 0, 0);
    __builtin_amdgcn_global_load_lds((gas_ptr)(Bbase + k0),          (las_ptr)(BsB + ldsoff),        16, 0, 0);
    __builtin_amdgcn_global_load_lds((gas_ptr)(Bbase + 64 * K + k0), (las_ptr)(BsB + 4096 + ldsoff), 16, 0, 0);
    __syncthreads();

    short8 a[4], bfr[4];
#pragma unroll
    for (int m = 0; m < 4; m++) a[m]   = *(const short8*)&As[(wr + m * 16 + lr16) * 32 + lk];
#pragma unroll
    for (int n = 0; n < 4; n++) bfr[n] = *(const short8*)&Bs[(wc + n * 16 + lr16) * 32 + lk];
#pragma unroll
    for (int m = 0; m < 4; m++)
#pragma unroll
      for (int n = 0; n < 4; n++)
        acc[m][n] = __builtin_amdgcn_mfma_f32_16x16x32_bf16(a[m], bfr[n], acc[m][n], 0, 0, 0);
    __syncthreads();
  }

  // epilogue: D[row][col], row=(l>>4)*4+j, col=l&15 within each 16x16 fragment
#pragma unroll
  for (int m = 0; m < 4; m++) {
#pragma unroll
    for (int n = 0; n < 4; n++) {
#pragma unroll
      for (int j = 0; j < 4; j++) {
        int R_ = row0 + wr + m * 16 + (l >> 4) * 4 + j;
        int C_ = col0 + wc + n * 16 + lr16;
        float v = acc[m][n][j];
        size_t o = (size_t)R_ * N + C_;
        if (EPI == 0) {
          outb[o] = f2bf(v);
        } else if (EPI == 1) {
          outf[o] = v + resid[o];
        } else if (EPI == 2) {
          float xx = v + bias[C_];
          outb[o] = f2bf(0.5f * xx * (1.0f + erff(xx * 0.70710678118f)));
        } else {
          outf[o] = v + bias[C_] + resid[o];
        }
      }
    }
  }
}

// ---------------- MFMA flash attention ----------------
// 256 threads = 4 waves; each wave owns 16 q-rows (64-row Q tile per block).
// KV tile = 64 keys. K staged via global_load_lds with pre-swizzled source
// (chunk ^= key&7); V transposed into LDS via registers with chunk ^= (d>>3)&7;
// P converted C-layout -> A-layout via per-wave LDS (stride 72 shorts = 144B).
__global__ __launch_bounds__(256) void attn_mfma(const short* __restrict__ qkv, short* __restrict__ ctx) {
  __shared__ alignas(16) short Ks[64 * 64];        // 8 KB, row stride 128 B (8 swizzled 16B chunks)
  __shared__ alignas(16) short Vt[64 * 72];        // 9 KB, V^T: row=d (stride 144 B), swizzled chunks
  __shared__ alignas(16) short Pl[4][16 * 72];     // 9 KB, per-wave P (stride 144 B)
  const int t = threadIdx.x;
  const int l = t & 63;
  const int w = t >> 6;
  const int l15 = l & 15, l4 = l >> 4;
  const int b = blockIdx.y >> 4, h = blockIdx.y & 15;
  const int qt = blockIdx.x;
  const int q0 = qt * 64 + w * 16;                 // this wave's q base

  const short* base = qkv + (size_t)b * SEQ * 3072 + h * 64;

  // Q fragments (A-layout): row = l15, dims c*32 + l4*8 .. +8
  short8 qf[2];
#pragma unroll
  for (int c = 0; c < 2; c++)
    qf[c] = *(const short8*)(base + (size_t)(q0 + l15) * 3072 + c * 32 + l4 * 8);

  // V staging assignment: thread holds keys {2vr, 2vr+1} x dims vd0..vd0+7
  const int vr = t >> 3;                           // 0..31
  const int vd0 = (t & 7) * 8;
  const short* vbase = base + 2048 + vd0;
  short8 va = *(const short8*)(vbase + (size_t)(2 * vr) * 3072);
  short8 vb = *(const short8*)(vbase + (size_t)(2 * vr + 1) * 3072);

  f32x4 acc[4] = {};
  float mrun[4] = {-1e30f, -1e30f, -1e30f, -1e30f};
  float lrun[4] = {0.f, 0.f, 0.f, 0.f};

  char* KsB = (char*)Ks;
  char* VtB = (char*)Vt;
  char* PlB = (char*)&Pl[w][0];

  for (int kt = 0; kt <= qt; ++kt) {
    __syncthreads();                               // all waves done reading prev K/V
    // stage K: granule g -> LDS byte g*16; source chunk = (g&7) ^ (key&7)
#pragma unroll
    for (int i = 0; i < 2; i++) {
      int g = (w * 2 + i) * 64 + l;                // 0..511
      int key = g >> 3, ck = g & 7;
      const short* src = base + (size_t)(kt * 64 + key) * 3072 + 1024 + ((ck ^ (key & 7)) * 8);
      __builtin_amdgcn_global_load_lds((gas_ptr)src, (las_ptr)(KsB + g * 16), 16, 0, 0);
    }
    // write V^T from regs: 8x b32 (two keys packed), chunk swizzled by (d>>3)&7
#pragma unroll
    for (int i = 0; i < 8; i++) {
      int d = vd0 + i;
      int cs = (vr >> 2) ^ ((d >> 3) & 7);
      uint32_t val = (uint32_t)(uint16_t)va[i] | ((uint32_t)(uint16_t)vb[i] << 16);
      *(uint32_t*)(VtB + d * 144 + cs * 16 + (vr & 3) * 4) = val;
    }
    // prefetch next tile's V into regs (latency spans the barrier drain)
    if (kt < qt) {
      va = *(const short8*)(vbase + (size_t)(kt * 64 + 64 + 2 * vr) * 3072);
      vb = *(const short8*)(vbase + (size_t)(kt * 64 + 64 + 2 * vr + 1) * 3072);
    }
    __syncthreads();                               // staging visible (vmcnt+lgkm drained)

    // QK^T: S[16 q][64 k], 8 MFMAs
    f32x4 sc[4];
#pragma unroll
    for (int cb = 0; cb < 4; cb++) {
      f32x4 s = {};
      int key = cb * 16 + l15;
#pragma unroll
      for (int c = 0; c < 2; c++) {
        int ck = (c * 4 + l4) ^ (key & 7);
        short8 kf = *(const short8*)(KsB + key * 128 + ck * 16);
        s = __builtin_amdgcn_mfma_f32_16x16x32_bf16(qf[c], kf, s, 0, 0, 0);
      }
      sc[cb] = s;
    }

    // online softmax in C-layout (lane holds rows l4*4+jj, col l15)
    const bool lastt = (kt == qt);
    float alpha[4];
#pragma unroll
    for (int jj = 0; jj < 4; jj++) {
      int qg = q0 + l4 * 4 + jj;
      float s0 = sc[0][jj] * 0.125f;
      float s1 = sc[1][jj] * 0.125f;
      float s2 = sc[2][jj] * 0.125f;
      float s3 = sc[3][jj] * 0.125f;
      if (lastt) {
        int kg = kt * 64 + l15;
        if (kg      > qg) s0 = -1e30f;
        if (kg + 16 > qg) s1 = -1e30f;
        if (kg + 32 > qg) s2 = -1e30f;
        if (kg + 48 > qg) s3 = -1e30f;
      }
      float rm = fmaxf(fmaxf(s0, s1), fmaxf(s2, s3));
      rm = fmaxf(rm, __shfl_xor(rm, 1));
      rm = fmaxf(rm, __shfl_xor(rm, 2));
      rm = fmaxf(rm, __shfl_xor(rm, 4));
      rm = fmaxf(rm, __shfl_xor(rm, 8));
      float nm = fmaxf(mrun[jj], rm);
      float al = __expf(mrun[jj] - nm);
      mrun[jj] = nm;
      float p0 = __expf(s0 - nm), p1 = __expf(s1 - nm);
      float p2 = __expf(s2 - nm), p3 = __expf(s3 - nm);
      float ps = p0 + p1 + p2 + p3;
      ps += __shfl_xor(ps, 1);
      ps += __shfl_xor(ps, 2);
      ps += __shfl_xor(ps, 4);
      ps += __shfl_xor(ps, 8);
      lrun[jj] = lrun[jj] * al + ps;
      alpha[jj] = al;
      short* pr = (short*)(PlB + (l4 * 4 + jj) * 144);
      pr[l15]      = f2bf(p0);
      pr[16 + l15] = f2bf(p1);
      pr[32 + l15] = f2bf(p2);
      pr[48 + l15] = f2bf(p3);
    }
#pragma unroll
    for (int db = 0; db < 4; db++) {
      f32x4 a = acc[db];
      a[0] *= alpha[0]; a[1] *= alpha[1]; a[2] *= alpha[2]; a[3] *= alpha[3];
      acc[db] = a;
    }
    // PV: ctx[16 q][64 d] += P(16x64) . V(64x64), 8 MFMAs
    // (same-wave DS write->read: LDS unit processes wave ops in order)
#pragma unroll
    for (int kc = 0; kc < 2; kc++) {
      short8 pf = *(const short8*)(PlB + l15 * 144 + kc * 64 + l4 * 16);
#pragma unroll
      for (int db = 0; db < 4; db++) {
        int d = db * 16 + l15;
        int cs = (kc * 4 + l4) ^ ((d >> 3) & 7);
        short8 vf = *(const short8*)(VtB + d * 144 + cs * 16);
        acc[db] = __builtin_amdgcn_mfma_f32_16x16x32_bf16(pf, vf, acc[db], 0, 0, 0);
      }
    }
  }

  float inv[4];
#pragma unroll
  for (int jj = 0; jj < 4; jj++) inv[jj] = 1.0f / lrun[jj];
  short* obase = ctx + (size_t)(b * SEQ + q0) * D_MODEL + h * 64;
#pragma unroll
  for (int db = 0; db < 4; db++)
#pragma unroll
    for (int jj = 0; jj < 4; jj++)
      obase[(size_t)(l4 * 4 + jj) * D_MODEL + db * 16 + l15] = f2bf(acc[db][jj] * inv[jj]);
}

extern "C" void kernel_launch(void* const* d_in, const int* in_sizes, int n_in,
                              void* d_out, int out_size, void* d_ws, size_t ws_size,
                              hipStream_t stream) {
  (void)in_sizes; (void)n_in; (void)out_size; (void)ws_size;
  const float* x    = (const float*)d_in[0];
  const float* WQ   = (const float*)d_in[1];
  const float* WK   = (const float*)d_in[2];
  const float* WV   = (const float*)d_in[3];
  const float* WO   = (const float*)d_in[4];
  const float* W1   = (const float*)d_in[5];
  const float* b1   = (const float*)d_in[6];
  const float* W2   = (const float*)d_in[7];
  const float* b2   = (const float*)d_in[8];
  const float* ln1w = (const float*)d_in[9];
  const float* ln1b = (const float*)d_in[10];
  const float* ln2w = (const float*)d_in[11];
  const float* ln2b = (const float*)d_in[12];
  float* out = (float*)d_out;

  char* p = (char*)d_ws;
  short* h1    = (short*)p; p += (size_t)ROWS * D_MODEL * 2;        // 8 MB
  short* ctx   = (short*)p; p += (size_t)ROWS * D_MODEL * 2;        // 8 MB
  short* h2    = (short*)p; p += (size_t)ROWS * D_MODEL * 2;        // 8 MB
  short* m1    = (short*)p; p += (size_t)ROWS * DMLP * 2;           // 32 MB
  short* wqkvT = (short*)p; p += (size_t)3 * D_MODEL * D_MODEL * 2; // 6 MB
  short* woT   = (short*)p; p += (size_t)D_MODEL * D_MODEL * 2;     // 2 MB
  short* w1T   = (short*)p; p += (size_t)D_MODEL * DMLP * 2;        // 8 MB
  short* w2T   = (short*)p; p += (size_t)D_MODEL * DMLP * 2;        // 8 MB
  short* qkv   = (short*)p; p += (size_t)ROWS * 3 * D_MODEL * 2;    // 24 MB

  // weight repacks (bf16, B^T layout)
  repack_qkv<<<3 * D_MODEL * D_MODEL / 256, 256, 0, stream>>>(WQ, WK, WV, wqkvT);
  transpose_cvt<<<D_MODEL * D_MODEL / 256, 256, 0, stream>>>(WO, woT, D_MODEL, 10);
  transpose_cvt<<<D_MODEL * DMLP / 256, 256, 0, stream>>>(W1, w1T, D_MODEL, 12);
  transpose_cvt<<<D_MODEL * DMLP / 256, 256, 0, stream>>>(W2, w2T, DMLP, 10);

  // LN1
  ln_kernel<<<ROWS, 256, 0, stream>>>(x, ln1w, ln1b, h1);
  // QKV projection: [4096,1024] x [1024,3072] -> bf16 qkv
  gemm_bt<0><<<dim3(3 * D_MODEL / 128, ROWS / 128), 256, 0, stream>>>(
      h1, wqkvT, nullptr, nullptr, nullptr, qkv, ROWS, 3 * D_MODEL, D_MODEL);
  // attention (MFMA flash)
  attn_mfma<<<dim3(SEQ / 64, BATCH * NHEADS), 256, 0, stream>>>(qkv, ctx);
  // output projection + residual -> x1 (d_out, f32)
  gemm_bt<1><<<dim3(D_MODEL / 128, ROWS / 128), 256, 0, stream>>>(
      ctx, woT, nullptr, x, out, nullptr, ROWS, D_MODEL, D_MODEL);
  // LN2
  ln_kernel<<<ROWS, 256, 0, stream>>>(out, ln2w, ln2b, h2);
  // MLP fc1 + GELU -> bf16 m1
  gemm_bt<2><<<dim3(DMLP / 128, ROWS / 128), 256, 0, stream>>>(
      h2, w1T, b1, nullptr, nullptr, m1, ROWS, DMLP, D_MODEL);
  // MLP fc2 + bias + residual -> d_out (f32)
  gemm_bt<3><<<dim3(D_MODEL / 128, ROWS / 128), 256, 0, stream>>>(
      m1, w2T, b2, out, out, nullptr, ROWS, D_MODEL, DMLP);
}

// Round 3
// 362.079 us; speedup vs baseline: 2.6147x; 1.1593x over previous
//
#include <hip/hip_runtime.h>
#include <hip/hip_bf16.h>
#include <cstdint>

#define D_MODEL 1024
#define NHEADS 16
#define DHEAD 64
#define DMLP 4096
#define BATCH 2
#define SEQ 2048
#define ROWS (BATCH*SEQ)
#define LN_EPS 1e-5f

typedef __attribute__((ext_vector_type(8))) short short8;
typedef __attribute__((ext_vector_type(4))) float f32x4;

typedef const __attribute__((address_space(1))) uint32_t* gas_ptr;
typedef __attribute__((address_space(3))) uint32_t* las_ptr;

__device__ __forceinline__ short f2bf(float f) {
  union { float f; uint32_t u; } v; v.f = f;
  uint32_t r = v.u + 0x7FFFu + ((v.u >> 16) & 1u);
  return (short)(r >> 16);
}
__device__ __forceinline__ float bf2f(short s) {
  union { uint32_t u; float f; } v; v.u = ((uint32_t)(uint16_t)s) << 16;
  return v.f;
}

// ---------------- LayerNorm: one block per row, 256 threads, D=1024 ----------------
__global__ void ln_kernel(const float* __restrict__ x, const float* __restrict__ w,
                          const float* __restrict__ b, short* __restrict__ out) {
  int row = blockIdx.x;
  int t = threadIdx.x;
  const float4 v = ((const float4*)(x + (size_t)row * D_MODEL))[t];
  float s = v.x + v.y + v.z + v.w;
  float s2 = v.x*v.x + v.y*v.y + v.z*v.z + v.w*v.w;
#pragma unroll
  for (int k = 1; k < 64; k <<= 1) { s += __shfl_xor(s, k); s2 += __shfl_xor(s2, k); }
  __shared__ float red[8];
  int wv = t >> 6;
  if ((t & 63) == 0) { red[wv] = s; red[wv + 4] = s2; }
  __syncthreads();
  s = red[0] + red[1] + red[2] + red[3];
  s2 = red[4] + red[5] + red[6] + red[7];
  float mu = s * (1.0f / D_MODEL);
  float var = s2 * (1.0f / D_MODEL) - mu * mu;
  float rstd = rsqrtf(var + LN_EPS);
  const float4 wv4 = ((const float4*)w)[t];
  const float4 bv4 = ((const float4*)b)[t];
  short4 o4;
  o4.x = f2bf((v.x - mu) * rstd * wv4.x + bv4.x);
  o4.y = f2bf((v.y - mu) * rstd * wv4.y + bv4.y);
  o4.z = f2bf((v.z - mu) * rstd * wv4.z + bv4.z);
  o4.w = f2bf((v.w - mu) * rstd * wv4.w + bv4.w);
  *(short4*)(out + (size_t)row * D_MODEL + t * 4) = o4;
}

// ---------------- Weight repack: WQ/WK/WV -> bf16 B^T [3072][1024] ----------------
__global__ void repack_qkv(const float* __restrict__ WQ, const float* __restrict__ WK,
                           const float* __restrict__ WV, short* __restrict__ out) {
  int id = blockIdx.x * 256 + threadIdx.x;     // over 3072*1024
  int d = id & 1023;           // k index
  int n = id >> 10;            // output col 0..3071
  int proj = n >> 10;
  int he = n & 1023;
  int h = he >> 6, e = he & 63;
  const float* W = (proj == 0) ? WQ : ((proj == 1) ? WK : WV);
  out[id] = f2bf(W[h * (D_MODEL * DHEAD) + d * DHEAD + e]);
}

// generic transpose+convert: src[R][C] f32 -> dst[C][R] bf16   (C = 1<<Cbits)
__global__ void transpose_cvt(const float* __restrict__ src, short* __restrict__ dst,
                              int R, int Cbits) {
  int id = blockIdx.x * 256 + threadIdx.x;
  int r = id >> Cbits;
  int c = id & ((1 << Cbits) - 1);
  dst[(size_t)c * R + r] = f2bf(src[id]);
}

// ---------------- bf16 MFMA GEMM, 128x128 tile, BK=32, B^T input ----------------
// EPI 0: bf16 store (outb)          EPI 1: f32 store + resid (outf)
// EPI 2: bias+GELU -> bf16 (outb)   EPI 3: bias + resid -> f32 (outf)
template<int EPI>
__global__ __launch_bounds__(256) void gemm_bt(const short* __restrict__ A, const short* __restrict__ BT,
                        const float* __restrict__ bias, const float* __restrict__ resid,
                        float* __restrict__ outf, short* __restrict__ outb,
                        int M, int N, int K) {
  __shared__ alignas(16) short As[128 * 32];
  __shared__ alignas(16) short Bs[128 * 32];
  const int t = threadIdx.x;
  const int l = t & 63;
  const int w = t >> 6;
  const int row0 = blockIdx.y * 128, col0 = blockIdx.x * 128;

  f32x4 acc[4][4] = {};

  const int srow = w * 16 + (l >> 2);          // 0..63
  const int schunk = (l & 3) * 8;              // k offset in elements
  const short* Abase = A + (size_t)(row0 + srow) * K + schunk;
  const short* Bbase = BT + (size_t)(col0 + srow) * K + schunk;
  char* AsB = (char*)As;
  char* BsB = (char*)Bs;
  const int ldsoff = w * 1024 + l * 16;        // bytes, linear per wave

  const int wr = (w >> 1) * 64, wc = (w & 1) * 64;
  const int lk = (l >> 4) * 8;
  const int lr16 = l & 15;

  for (int k0 = 0; k0 < K; k0 += 32) {
    __builtin_amdgcn_global_load_lds((gas_ptr)(Abase + k0),          (las_ptr)(AsB + ldsoff),        16, 0, 0);
    __builtin_amdgcn_global_load_lds((gas_ptr)(Abase + 64 * K + k0), (las_ptr)(AsB + 4096 + ldsoff), 16, 0, 0);
    __builtin_amdgcn_global_load_lds((gas_ptr)(Bbase + k0),          (las_ptr)(BsB + ldsoff),        16, 0, 0);
    __builtin_amdgcn_global_load_lds((gas_ptr)(Bbase + 64 * K + k0), (las_ptr)(BsB + 4096 + ldsoff), 16, 0, 0);
    __syncthreads();

    short8 a[4], bfr[4];
#pragma unroll
    for (int m = 0; m < 4; m++) a[m]   = *(const short8*)&As[(wr + m * 16 + lr16) * 32 + lk];
#pragma unroll
    for (int n = 0; n < 4; n++) bfr[n] = *(const short8*)&Bs[(wc + n * 16 + lr16) * 32 + lk];
#pragma unroll
    for (int m = 0; m < 4; m++)
#pragma unroll
      for (int n = 0; n < 4; n++)
        acc[m][n] = __builtin_amdgcn_mfma_f32_16x16x32_bf16(a[m], bfr[n], acc[m][n], 0, 0, 0);
    __syncthreads();
  }

  // epilogue: D[row][col], row=(l>>4)*4+j, col=l&15 within each 16x16 fragment
#pragma unroll
  for (int m = 0; m < 4; m++) {
#pragma unroll
    for (int n = 0; n < 4; n++) {
#pragma unroll
      for (int j = 0; j < 4; j++) {
        int R_ = row0 + wr + m * 16 + (l >> 4) * 4 + j;
        int C_ = col0 + wc + n * 16 + lr16;
        float v = acc[m][n][j];
        size_t o = (size_t)R_ * N + C_;
        if (EPI == 0) {
          outb[o] = f2bf(v);
        } else if (EPI == 1) {
          outf[o] = v + resid[o];
        } else if (EPI == 2) {
          float xx = v + bias[C_];
          outb[o] = f2bf(0.5f * xx * (1.0f + erff(xx * 0.70710678118f)));
        } else {
          outf[o] = v + bias[C_] + resid[o];
        }
      }
    }
  }
}

// ---------------- MFMA flash attention, 2-phase pipelined ----------------
// 4 waves, wave owns 16 q-rows (64-row Q tile). KV tile = 64 keys.
// Ks/Vt double-buffered in LDS; tile kt+1 staged (K gload_lds, V via regs one
// tile deeper) at top of iteration kt; ONE __syncthreads per iteration at the
// end (drain lands after the full compute phase -> latency hidden).
__device__ __forceinline__ void attn_step(
    int kt_, int qt, int bufP,
    const short* __restrict__ base, const short* __restrict__ vbase,
    short8& vWA, short8& vWB,          // V[kt_+1] regs -> write Vt[bufQ]
    short8& vLA, short8& vLB,          // target regs for V[kt_+2] load
    const short8 qf[2],
    char* KsB, char* VtB, char* PlB,
    f32x4 acc[4], float mrun[4], float lrun[4], float* alphaOut,
    int w, int l, int q0, int vr, int vd0)
{
  const int l15 = l & 15, l4 = l >> 4;
  const int bufQ = bufP ^ 1;
  if (kt_ < qt) {
    // write V^T[kt_+1] into Vt[bufQ], chunk-swizzled
#pragma unroll
    for (int i = 0; i < 8; i++) {
      int d = vd0 + i;
      int cs = (vr >> 2) ^ ((d >> 3) & 7);
      uint32_t val = (uint32_t)(uint16_t)vWA[i] | ((uint32_t)(uint16_t)vWB[i] << 16);
      *(uint32_t*)(VtB + bufQ * 9216 + d * 144 + cs * 16 + (vr & 3) * 4) = val;
    }
    // stage K[kt_+1] -> Ks[bufQ] (pre-swizzled source)
#pragma unroll
    for (int i = 0; i < 2; i++) {
      int g = (w * 2 + i) * 64 + l;
      int key = g >> 3, ck = g & 7;
      const short* src = base + (size_t)((kt_ + 1) * 64 + key) * 3072 + 1024 + ((ck ^ (key & 7)) * 8);
      __builtin_amdgcn_global_load_lds((gas_ptr)src, (las_ptr)(KsB + bufQ * 8192 + g * 16), 16, 0, 0);
    }
  }
  if (kt_ + 2 <= qt) {
    vLA = *(const short8*)(vbase + (size_t)((kt_ + 2) * 64 + 2 * vr) * 3072);
    vLB = *(const short8*)(vbase + (size_t)((kt_ + 2) * 64 + 2 * vr + 1) * 3072);
  }

  // ---- compute tile kt_ on Ks[bufP], Vt[bufP] ----
  f32x4 sc[4];
#pragma unroll
  for (int cb = 0; cb < 4; cb++) {
    f32x4 s = {};
    int key = cb * 16 + l15;
#pragma unroll
    for (int c = 0; c < 2; c++) {
      int ck = (c * 4 + l4) ^ (key & 7);
      short8 kf = *(const short8*)(KsB + bufP * 8192 + key * 128 + ck * 16);
      s = __builtin_amdgcn_mfma_f32_16x16x32_bf16(qf[c], kf, s, 0, 0, 0);
    }
    sc[cb] = s;
  }

  const bool lastt = (kt_ == qt);
  float alpha[4];
#pragma unroll
  for (int jj = 0; jj < 4; jj++) {
    int qg = q0 + l4 * 4 + jj;
    float s0 = sc[0][jj] * 0.125f;
    float s1 = sc[1][jj] * 0.125f;
    float s2 = sc[2][jj] * 0.125f;
    float s3 = sc[3][jj] * 0.125f;
    if (lastt) {
      int kg = kt_ * 64 + l15;
      if (kg      > qg) s0 = -1e30f;
      if (kg + 16 > qg) s1 = -1e30f;
      if (kg + 32 > qg) s2 = -1e30f;
      if (kg + 48 > qg) s3 = -1e30f;
    }
    float rm = fmaxf(fmaxf(s0, s1), fmaxf(s2, s3));
    rm = fmaxf(rm, __shfl_xor(rm, 1));
    rm = fmaxf(rm, __shfl_xor(rm, 2));
    rm = fmaxf(rm, __shfl_xor(rm, 4));
    rm = fmaxf(rm, __shfl_xor(rm, 8));
    float nm = fmaxf(mrun[jj], rm);
    float al = __expf(mrun[jj] - nm);
    mrun[jj] = nm;
    float p0 = __expf(s0 - nm), p1 = __expf(s1 - nm);
    float p2 = __expf(s2 - nm), p3 = __expf(s3 - nm);
    float ps = p0 + p1 + p2 + p3;
    ps += __shfl_xor(ps, 1);
    ps += __shfl_xor(ps, 2);
    ps += __shfl_xor(ps, 4);
    ps += __shfl_xor(ps, 8);
    lrun[jj] = lrun[jj] * al + ps;
    alpha[jj] = al;
    short* pr = (short*)(PlB + (l4 * 4 + jj) * 144);
    pr[l15]      = f2bf(p0);
    pr[16 + l15] = f2bf(p1);
    pr[32 + l15] = f2bf(p2);
    pr[48 + l15] = f2bf(p3);
  }
#pragma unroll
  for (int db = 0; db < 4; db++) {
    f32x4 a = acc[db];
    a[0] *= alpha[0]; a[1] *= alpha[1]; a[2] *= alpha[2]; a[3] *= alpha[3];
    acc[db] = a;
  }
  // PV: same-wave DS write->read on Pl (LDS processes wave ops in order)
#pragma unroll
  for (int kc = 0; kc < 2; kc++) {
    short8 pf = *(const short8*)(PlB + l15 * 144 + kc * 64 + l4 * 16);
#pragma unroll
    for (int db = 0; db < 4; db++) {
      int d = db * 16 + l15;
      int cs = (kc * 4 + l4) ^ ((d >> 3) & 7);
      short8 vf = *(const short8*)(VtB + bufP * 9216 + d * 144 + cs * 16);
      acc[db] = __builtin_amdgcn_mfma_f32_16x16x32_bf16(pf, vf, acc[db], 0, 0, 0);
    }
  }
  (void)alphaOut;
}

__global__ __launch_bounds__(256) void attn_mfma(const short* __restrict__ qkv, short* __restrict__ ctx) {
  __shared__ alignas(16) short Ks[2 * 64 * 64];    // 16 KB (double-buffered)
  __shared__ alignas(16) short Vt[2 * 64 * 72];    // 18 KB (double-buffered)
  __shared__ alignas(16) short Pl[4][16 * 72];     // 9 KB, per-wave P
  const int t = threadIdx.x;
  const int l = t & 63;
  const int w = t >> 6;
  const int l15 = l & 15, l4 = l >> 4;
  const int bh = blockIdx.x;                       // bh fastest: spreads qt across CUs
  const int b = bh >> 4, h = bh & 15;
  const int qt = (gridDim.y - 1) - blockIdx.y;     // heavy tiles first (LPT backfill)
  const int q0 = qt * 64 + w * 16;

  const short* base = qkv + (size_t)b * SEQ * 3072 + h * 64;

  short8 qf[2];
#pragma unroll
  for (int c = 0; c < 2; c++)
    qf[c] = *(const short8*)(base + (size_t)(q0 + l15) * 3072 + c * 32 + l4 * 8);

  const int vr = t >> 3;                           // 0..31
  const int vd0 = (t & 7) * 8;
  const short* vbase = base + 2048 + vd0;

  char* KsB = (char*)Ks;
  char* VtB = (char*)Vt;
  char* PlB = (char*)&Pl[w][0];

  // prologue: V[0] (+V[1]) to regs, Vt[0] write, K[0] stage
  short8 va0, vb0, va1, vb1;
  va0 = *(const short8*)(vbase + (size_t)(2 * vr) * 3072);
  vb0 = *(const short8*)(vbase + (size_t)(2 * vr + 1) * 3072);
  if (qt >= 1) {
    va1 = *(const short8*)(vbase + (size_t)(64 + 2 * vr) * 3072);
    vb1 = *(const short8*)(vbase + (size_t)(64 + 2 * vr + 1) * 3072);
  }
#pragma unroll
  for (int i = 0; i < 8; i++) {
    int d = vd0 + i;
    int cs = (vr >> 2) ^ ((d >> 3) & 7);
    uint32_t val = (uint32_t)(uint16_t)va0[i] | ((uint32_t)(uint16_t)vb0[i] << 16);
    *(uint32_t*)(VtB + d * 144 + cs * 16 + (vr & 3) * 4) = val;
  }
#pragma unroll
  for (int i = 0; i < 2; i++) {
    int g = (w * 2 + i) * 64 + l;
    int key = g >> 3, ck = g & 7;
    const short* src = base + (size_t)key * 3072 + 1024 + ((ck ^ (key & 7)) * 8);
    __builtin_amdgcn_global_load_lds((gas_ptr)src, (las_ptr)(KsB + g * 16), 16, 0, 0);
  }
  __syncthreads();

  f32x4 acc[4] = {};
  float mrun[4] = {-1e30f, -1e30f, -1e30f, -1e30f};
  float lrun[4] = {0.f, 0.f, 0.f, 0.f};

  int kt = 0;
  while (true) {
    attn_step(kt, qt, 0, base, vbase, va1, vb1, va0, vb0, qf,
              KsB, VtB, PlB, acc, mrun, lrun, nullptr, w, l, q0, vr, vd0);
    __syncthreads();
    if (++kt > qt) break;
    attn_step(kt, qt, 1, base, vbase, va0, vb0, va1, vb1, qf,
              KsB, VtB, PlB, acc, mrun, lrun, nullptr, w, l, q0, vr, vd0);
    __syncthreads();
    if (++kt > qt) break;
  }

  float inv[4];
#pragma unroll
  for (int jj = 0; jj < 4; jj++) inv[jj] = 1.0f / lrun[jj];
  short* obase = ctx + (size_t)(b * SEQ + q0) * D_MODEL + h * 64;
#pragma unroll
  for (int db = 0; db < 4; db++)
#pragma unroll
    for (int jj = 0; jj < 4; jj++)
      obase[(size_t)(l4 * 4 + jj) * D_MODEL + db * 16 + l15] = f2bf(acc[db][jj] * inv[jj]);
}

extern "C" void kernel_launch(void* const* d_in, const int* in_sizes, int n_in,
                              void* d_out, int out_size, void* d_ws, size_t ws_size,
                              hipStream_t stream) {
  (void)in_sizes; (void)n_in; (void)out_size; (void)ws_size;
  const float* x    = (const float*)d_in[0];
  const float* WQ   = (const float*)d_in[1];
  const float* WK   = (const float*)d_in[2];
  const float* WV   = (const float*)d_in[3];
  const float* WO   = (const float*)d_in[4];
  const float* W1   = (const float*)d_in[5];
  const float* b1   = (const float*)d_in[6];
  const float* W2   = (const float*)d_in[7];
  const float* b2   = (const float*)d_in[8];
  const float* ln1w = (const float*)d_in[9];
  const float* ln1b = (const float*)d_in[10];
  const float* ln2w = (const float*)d_in[11];
  const float* ln2b = (const float*)d_in[12];
  float* out = (float*)d_out;

  char* p = (char*)d_ws;
  short* h1    = (short*)p; p += (size_t)ROWS * D_MODEL * 2;        // 8 MB
  short* ctx   = (short*)p; p += (size_t)ROWS * D_MODEL * 2;        // 8 MB
  short* h2    = (short*)p; p += (size_t)ROWS * D_MODEL * 2;        // 8 MB
  short* m1    = (short*)p; p += (size_t)ROWS * DMLP * 2;           // 32 MB
  short* wqkvT = (short*)p; p += (size_t)3 * D_MODEL * D_MODEL * 2; // 6 MB
  short* woT   = (short*)p; p += (size_t)D_MODEL * D_MODEL * 2;     // 2 MB
  short* w1T   = (short*)p; p += (size_t)D_MODEL * DMLP * 2;        // 8 MB
  short* w2T   = (short*)p; p += (size_t)D_MODEL * DMLP * 2;        // 8 MB
  short* qkv   = (short*)p; p += (size_t)ROWS * 3 * D_MODEL * 2;    // 24 MB

  // weight repacks (bf16, B^T layout)
  repack_qkv<<<3 * D_MODEL * D_MODEL / 256, 256, 0, stream>>>(WQ, WK, WV, wqkvT);
  transpose_cvt<<<D_MODEL * D_MODEL / 256, 256, 0, stream>>>(WO, woT, D_MODEL, 10);
  transpose_cvt<<<D_MODEL * DMLP / 256, 256, 0, stream>>>(W1, w1T, D_MODEL, 12);
  transpose_cvt<<<D_MODEL * DMLP / 256, 256, 0, stream>>>(W2, w2T, DMLP, 10);

  // LN1
  ln_kernel<<<ROWS, 256, 0, stream>>>(x, ln1w, ln1b, h1);
  // QKV projection: [4096,1024] x [1024,3072] -> bf16 qkv
  gemm_bt<0><<<dim3(3 * D_MODEL / 128, ROWS / 128), 256, 0, stream>>>(
      h1, wqkvT, nullptr, nullptr, nullptr, qkv, ROWS, 3 * D_MODEL, D_MODEL);
  // attention (MFMA flash, pipelined; grid transposed: bh fastest, qt reversed)
  attn_mfma<<<dim3(BATCH * NHEADS, SEQ / 64), 256, 0, stream>>>(qkv, ctx);
  // output projection + residual -> x1 (d_out, f32)
  gemm_bt<1><<<dim3(D_MODEL / 128, ROWS / 128), 256, 0, stream>>>(
      ctx, woT, nullptr, x, out, nullptr, ROWS, D_MODEL, D_MODEL);
  // LN2
  ln_kernel<<<ROWS, 256, 0, stream>>>(out, ln2w, ln2b, h2);
  // MLP fc1 + GELU -> bf16 m1
  gemm_bt<2><<<dim3(DMLP / 128, ROWS / 128), 256, 0, stream>>>(
      h2, w1T, b1, nullptr, nullptr, m1, ROWS, DMLP, D_MODEL);
  // MLP fc2 + bias + residual -> d_out (f32)
  gemm_bt<3><<<dim3(D_MODEL / 128, ROWS / 128), 256, 0, stream>>>(
      m1, w2T, b2, out, out, nullptr, ROWS, D_MODEL, DMLP);
}

// Round 4
// 308.119 us; speedup vs baseline: 3.0726x; 1.1751x over previous
//
#include <hip/hip_runtime.h>
#include <hip/hip_bf16.h>
#include <cstdint>

#define D_MODEL 1024
#define NHEADS 16
#define DHEAD 64
#define DMLP 4096
#define BATCH 2
#define SEQ 2048
#define ROWS (BATCH*SEQ)
#define LN_EPS 1e-5f

typedef __attribute__((ext_vector_type(8))) short short8;
typedef __attribute__((ext_vector_type(4))) float f32x4;

typedef const __attribute__((address_space(1))) uint32_t* gas_ptr;
typedef __attribute__((address_space(3))) uint32_t* las_ptr;

__device__ __forceinline__ short f2bf(float f) {
  union { float f; uint32_t u; } v; v.f = f;
  uint32_t r = v.u + 0x7FFFu + ((v.u >> 16) & 1u);
  return (short)(r >> 16);
}
__device__ __forceinline__ float bf2f(short s) {
  union { uint32_t u; float f; } v; v.u = ((uint32_t)(uint16_t)s) << 16;
  return v.f;
}

// ---------------- LayerNorm: one block per row, 256 threads, D=1024 ----------------
__global__ void ln_kernel(const float* __restrict__ x, const float* __restrict__ w,
                          const float* __restrict__ b, short* __restrict__ out) {
  int row = blockIdx.x;
  int t = threadIdx.x;
  const float4 v = ((const float4*)(x + (size_t)row * D_MODEL))[t];
  float s = v.x + v.y + v.z + v.w;
  float s2 = v.x*v.x + v.y*v.y + v.z*v.z + v.w*v.w;
#pragma unroll
  for (int k = 1; k < 64; k <<= 1) { s += __shfl_xor(s, k); s2 += __shfl_xor(s2, k); }
  __shared__ float red[8];
  int wv = t >> 6;
  if ((t & 63) == 0) { red[wv] = s; red[wv + 4] = s2; }
  __syncthreads();
  s = red[0] + red[1] + red[2] + red[3];
  s2 = red[4] + red[5] + red[6] + red[7];
  float mu = s * (1.0f / D_MODEL);
  float var = s2 * (1.0f / D_MODEL) - mu * mu;
  float rstd = rsqrtf(var + LN_EPS);
  const float4 wv4 = ((const float4*)w)[t];
  const float4 bv4 = ((const float4*)b)[t];
  short4 o4;
  o4.x = f2bf((v.x - mu) * rstd * wv4.x + bv4.x);
  o4.y = f2bf((v.y - mu) * rstd * wv4.y + bv4.y);
  o4.z = f2bf((v.z - mu) * rstd * wv4.z + bv4.z);
  o4.w = f2bf((v.w - mu) * rstd * wv4.w + bv4.w);
  *(short4*)(out + (size_t)row * D_MODEL + t * 4) = o4;
}

// ---------------- Tiled transpose+convert ----------------
// src f32 [nmat][R][C] (matStride elems between mats) -> dst bf16 [nmat][C][R]
// 64x64 tiles via padded LDS; coalesced float4 reads, coalesced short4 writes.
__global__ __launch_bounds__(256) void transpose_tile(const float* __restrict__ src, short* __restrict__ dst,
                                                      int R, int C, int srcMatStride) {
  __shared__ float tile[64][65];
  const int m = blockIdx.z;
  const int r0 = blockIdx.y * 64, c0 = blockIdx.x * 64;
  const int tx = threadIdx.x & 15, ty = threadIdx.x >> 4;
  const float* s = src + (size_t)m * srcMatStride + (size_t)r0 * C + c0;
#pragma unroll
  for (int i = 0; i < 4; i++) {
    float4 v = *(const float4*)(s + (size_t)(ty + i * 16) * C + tx * 4);
    tile[ty + i * 16][tx * 4 + 0] = v.x;
    tile[ty + i * 16][tx * 4 + 1] = v.y;
    tile[ty + i * 16][tx * 4 + 2] = v.z;
    tile[ty + i * 16][tx * 4 + 3] = v.w;
  }
  __syncthreads();
  short* d = dst + (size_t)m * C * R + (size_t)c0 * R + r0;
#pragma unroll
  for (int p = 0; p < 4; p++) {
    int c = ty + p * 16;
    int r4 = tx * 4;
    short4 o;
    o.x = f2bf(tile[r4 + 0][c]);
    o.y = f2bf(tile[r4 + 1][c]);
    o.z = f2bf(tile[r4 + 2][c]);
    o.w = f2bf(tile[r4 + 3][c]);
    *(short4*)(d + (size_t)c * R + r4) = o;
  }
}

// ---------------- bf16 MFMA GEMM, 128x128 tile, BK=32, B^T input ----------------
// 2-phase pipelined: STAGE(t+1) issued before compute(t); one barrier per step.
// LDS chunk XOR-swizzle (both-sides): source chunk (l&3)^(srow&3), read chunk l4^(row&3).
// EPI 0: bf16 store (outb)          EPI 1: f32 store + resid (outf)
// EPI 2: bias+GELU -> bf16 (outb)   EPI 3: bias + resid -> f32 (outf)
template<int EPI>
__global__ __launch_bounds__(256) void gemm_bt(const short* __restrict__ A, const short* __restrict__ BT,
                        const float* __restrict__ bias, const float* __restrict__ resid,
                        float* __restrict__ outf, short* __restrict__ outb,
                        int M, int N, int K) {
  __shared__ alignas(16) short As[2][128 * 32];
  __shared__ alignas(16) short Bs[2][128 * 32];
  const int t = threadIdx.x;
  const int l = t & 63;
  const int w = t >> 6;
  const int row0 = blockIdx.y * 128, col0 = blockIdx.x * 128;

  f32x4 acc[4][4] = {};

  const int srow = w * 16 + (l >> 2);              // 0..63
  const int cs8 = ((l & 3) ^ (srow & 3)) * 8;      // pre-swizzled source chunk (elements)
  const short* Abase = A + (size_t)(row0 + srow) * K + cs8;
  const short* Bbase = BT + (size_t)(col0 + srow) * K + cs8;
  char* AsB = (char*)As;
  char* BsB = (char*)Bs;
  const int ldsoff = w * 1024 + l * 16;            // bytes, linear within 8KB buffer

  const int wr = (w >> 1) * 64, wc = (w & 1) * 64;
  const int l15 = l & 15, l4 = l >> 4;
  const int rchunk = (l4 ^ (l15 & 3)) * 8;         // read chunk: l4 ^ (row&3), row&3==l15&3

  // prologue: stage tile 0 into buf 0
  __builtin_amdgcn_global_load_lds((gas_ptr)(Abase),          (las_ptr)(AsB + ldsoff),        16, 0, 0);
  __builtin_amdgcn_global_load_lds((gas_ptr)(Abase + 64 * K), (las_ptr)(AsB + 4096 + ldsoff), 16, 0, 0);
  __builtin_amdgcn_global_load_lds((gas_ptr)(Bbase),          (las_ptr)(BsB + ldsoff),        16, 0, 0);
  __builtin_amdgcn_global_load_lds((gas_ptr)(Bbase + 64 * K), (las_ptr)(BsB + 4096 + ldsoff), 16, 0, 0);
  __syncthreads();

  const int nk = K >> 5;
  for (int ti = 0; ti < nk; ti++) {
    const int cur = ti & 1;
    if (ti + 1 < nk) {
      const int nb = (cur ^ 1) * 8192;
      const int k0 = (ti + 1) << 5;
      __builtin_amdgcn_global_load_lds((gas_ptr)(Abase + k0),          (las_ptr)(AsB + nb + ldsoff),        16, 0, 0);
      __builtin_amdgcn_global_load_lds((gas_ptr)(Abase + 64 * K + k0), (las_ptr)(AsB + nb + 4096 + ldsoff), 16, 0, 0);
      __builtin_amdgcn_global_load_lds((gas_ptr)(Bbase + k0),          (las_ptr)(BsB + nb + ldsoff),        16, 0, 0);
      __builtin_amdgcn_global_load_lds((gas_ptr)(Bbase + 64 * K + k0), (las_ptr)(BsB + nb + 4096 + ldsoff), 16, 0, 0);
    }
    const short* Ab = &As[cur][0];
    const short* Bb = &Bs[cur][0];
    short8 a[4], bfr[4];
#pragma unroll
    for (int m = 0; m < 4; m++) a[m]   = *(const short8*)&Ab[(wr + m * 16 + l15) * 32 + rchunk];
#pragma unroll
    for (int n = 0; n < 4; n++) bfr[n] = *(const short8*)&Bb[(wc + n * 16 + l15) * 32 + rchunk];
#pragma unroll
    for (int m = 0; m < 4; m++)
#pragma unroll
      for (int n = 0; n < 4; n++)
        acc[m][n] = __builtin_amdgcn_mfma_f32_16x16x32_bf16(a[m], bfr[n], acc[m][n], 0, 0, 0);
    __syncthreads();   // drains the prefetch (vmcnt0) after a full compute phase
  }

  // epilogue: D[row][col], row=(l>>4)*4+j, col=l&15 within each 16x16 fragment
#pragma unroll
  for (int m = 0; m < 4; m++) {
#pragma unroll
    for (int n = 0; n < 4; n++) {
#pragma unroll
      for (int j = 0; j < 4; j++) {
        int R_ = row0 + wr + m * 16 + l4 * 4 + j;
        int C_ = col0 + wc + n * 16 + l15;
        float v = acc[m][n][j];
        size_t o = (size_t)R_ * N + C_;
        if (EPI == 0) {
          outb[o] = f2bf(v);
        } else if (EPI == 1) {
          outf[o] = v + resid[o];
        } else if (EPI == 2) {
          float xx = v + bias[C_];
          outb[o] = f2bf(0.5f * xx * (1.0f + erff(xx * 0.70710678118f)));
        } else {
          outf[o] = v + bias[C_] + resid[o];
        }
      }
    }
  }
}

// ---------------- MFMA flash attention, 2-phase pipelined ----------------
__device__ __forceinline__ void attn_step(
    int kt_, int qt, int bufP,
    const short* __restrict__ base, const short* __restrict__ vbase,
    short8& vWA, short8& vWB,          // V[kt_+1] regs -> write Vt[bufQ]
    short8& vLA, short8& vLB,          // target regs for V[kt_+2] load
    const short8 qf[2],
    char* KsB, char* VtB, char* PlB,
    f32x4 acc[4], float mrun[4], float lrun[4],
    int w, int l, int q0, int vr, int vd0)
{
  const int l15 = l & 15, l4 = l >> 4;
  const int bufQ = bufP ^ 1;
  if (kt_ < qt) {
#pragma unroll
    for (int i = 0; i < 8; i++) {
      int d = vd0 + i;
      int cs = (vr >> 2) ^ ((d >> 3) & 7);
      uint32_t val = (uint32_t)(uint16_t)vWA[i] | ((uint32_t)(uint16_t)vWB[i] << 16);
      *(uint32_t*)(VtB + bufQ * 9216 + d * 144 + cs * 16 + (vr & 3) * 4) = val;
    }
#pragma unroll
    for (int i = 0; i < 2; i++) {
      int g = (w * 2 + i) * 64 + l;
      int key = g >> 3, ck = g & 7;
      const short* src = base + (size_t)((kt_ + 1) * 64 + key) * 3072 + 1024 + ((ck ^ (key & 7)) * 8);
      __builtin_amdgcn_global_load_lds((gas_ptr)src, (las_ptr)(KsB + bufQ * 8192 + g * 16), 16, 0, 0);
    }
  }
  if (kt_ + 2 <= qt) {
    vLA = *(const short8*)(vbase + (size_t)((kt_ + 2) * 64 + 2 * vr) * 3072);
    vLB = *(const short8*)(vbase + (size_t)((kt_ + 2) * 64 + 2 * vr + 1) * 3072);
  }

  f32x4 sc[4];
#pragma unroll
  for (int cb = 0; cb < 4; cb++) {
    f32x4 s = {};
    int key = cb * 16 + l15;
#pragma unroll
    for (int c = 0; c < 2; c++) {
      int ck = (c * 4 + l4) ^ (key & 7);
      short8 kf = *(const short8*)(KsB + bufP * 8192 + key * 128 + ck * 16);
      s = __builtin_amdgcn_mfma_f32_16x16x32_bf16(qf[c], kf, s, 0, 0, 0);
    }
    sc[cb] = s;
  }

  const bool lastt = (kt_ == qt);
  float alpha[4];
#pragma unroll
  for (int jj = 0; jj < 4; jj++) {
    int qg = q0 + l4 * 4 + jj;
    float s0 = sc[0][jj] * 0.125f;
    float s1 = sc[1][jj] * 0.125f;
    float s2 = sc[2][jj] * 0.125f;
    float s3 = sc[3][jj] * 0.125f;
    if (lastt) {
      int kg = kt_ * 64 + l15;
      if (kg      > qg) s0 = -1e30f;
      if (kg + 16 > qg) s1 = -1e30f;
      if (kg + 32 > qg) s2 = -1e30f;
      if (kg + 48 > qg) s3 = -1e30f;
    }
    float rm = fmaxf(fmaxf(s0, s1), fmaxf(s2, s3));
    rm = fmaxf(rm, __shfl_xor(rm, 1));
    rm = fmaxf(rm, __shfl_xor(rm, 2));
    rm = fmaxf(rm, __shfl_xor(rm, 4));
    rm = fmaxf(rm, __shfl_xor(rm, 8));
    float nm = fmaxf(mrun[jj], rm);
    float al = __expf(mrun[jj] - nm);
    mrun[jj] = nm;
    float p0 = __expf(s0 - nm), p1 = __expf(s1 - nm);
    float p2 = __expf(s2 - nm), p3 = __expf(s3 - nm);
    float ps = p0 + p1 + p2 + p3;
    ps += __shfl_xor(ps, 1);
    ps += __shfl_xor(ps, 2);
    ps += __shfl_xor(ps, 4);
    ps += __shfl_xor(ps, 8);
    lrun[jj] = lrun[jj] * al + ps;
    alpha[jj] = al;
    short* pr = (short*)(PlB + (l4 * 4 + jj) * 144);
    pr[l15]      = f2bf(p0);
    pr[16 + l15] = f2bf(p1);
    pr[32 + l15] = f2bf(p2);
    pr[48 + l15] = f2bf(p3);
  }
#pragma unroll
  for (int db = 0; db < 4; db++) {
    f32x4 a = acc[db];
    a[0] *= alpha[0]; a[1] *= alpha[1]; a[2] *= alpha[2]; a[3] *= alpha[3];
    acc[db] = a;
  }
#pragma unroll
  for (int kc = 0; kc < 2; kc++) {
    short8 pf = *(const short8*)(PlB + l15 * 144 + kc * 64 + l4 * 16);
#pragma unroll
    for (int db = 0; db < 4; db++) {
      int d = db * 16 + l15;
      int cs = (kc * 4 + l4) ^ ((d >> 3) & 7);
      short8 vf = *(const short8*)(VtB + bufP * 9216 + d * 144 + cs * 16);
      acc[db] = __builtin_amdgcn_mfma_f32_16x16x32_bf16(pf, vf, acc[db], 0, 0, 0);
    }
  }
}

__global__ __launch_bounds__(256) void attn_mfma(const short* __restrict__ qkv, short* __restrict__ ctx) {
  __shared__ alignas(16) short Ks[2 * 64 * 64];    // 16 KB (double-buffered)
  __shared__ alignas(16) short Vt[2 * 64 * 72];    // 18 KB (double-buffered)
  __shared__ alignas(16) short Pl[4][16 * 72];     // 9 KB, per-wave P
  const int t = threadIdx.x;
  const int l = t & 63;
  const int w = t >> 6;
  const int l15 = l & 15, l4 = l >> 4;
  const int bh = blockIdx.x;                       // bh fastest: spreads qt across CUs
  const int b = bh >> 4, h = bh & 15;
  const int qt = (gridDim.y - 1) - blockIdx.y;     // heavy tiles first (LPT backfill)
  const int q0 = qt * 64 + w * 16;

  const short* base = qkv + (size_t)b * SEQ * 3072 + h * 64;

  short8 qf[2];
#pragma unroll
  for (int c = 0; c < 2; c++)
    qf[c] = *(const short8*)(base + (size_t)(q0 + l15) * 3072 + c * 32 + l4 * 8);

  const int vr = t >> 3;                           // 0..31
  const int vd0 = (t & 7) * 8;
  const short* vbase = base + 2048 + vd0;

  char* KsB = (char*)Ks;
  char* VtB = (char*)Vt;
  char* PlB = (char*)&Pl[w][0];

  short8 va0, vb0, va1, vb1;
  va0 = *(const short8*)(vbase + (size_t)(2 * vr) * 3072);
  vb0 = *(const short8*)(vbase + (size_t)(2 * vr + 1) * 3072);
  if (qt >= 1) {
    va1 = *(const short8*)(vbase + (size_t)(64 + 2 * vr) * 3072);
    vb1 = *(const short8*)(vbase + (size_t)(64 + 2 * vr + 1) * 3072);
  }
#pragma unroll
  for (int i = 0; i < 8; i++) {
    int d = vd0 + i;
    int cs = (vr >> 2) ^ ((d >> 3) & 7);
    uint32_t val = (uint32_t)(uint16_t)va0[i] | ((uint32_t)(uint16_t)vb0[i] << 16);
    *(uint32_t*)(VtB + d * 144 + cs * 16 + (vr & 3) * 4) = val;
  }
#pragma unroll
  for (int i = 0; i < 2; i++) {
    int g = (w * 2 + i) * 64 + l;
    int key = g >> 3, ck = g & 7;
    const short* src = base + (size_t)key * 3072 + 1024 + ((ck ^ (key & 7)) * 8);
    __builtin_amdgcn_global_load_lds((gas_ptr)src, (las_ptr)(KsB + g * 16), 16, 0, 0);
  }
  __syncthreads();

  f32x4 acc[4] = {};
  float mrun[4] = {-1e30f, -1e30f, -1e30f, -1e30f};
  float lrun[4] = {0.f, 0.f, 0.f, 0.f};

  int kt = 0;
  while (true) {
    attn_step(kt, qt, 0, base, vbase, va1, vb1, va0, vb0, qf,
              KsB, VtB, PlB, acc, mrun, lrun, w, l, q0, vr, vd0);
    __syncthreads();
    if (++kt > qt) break;
    attn_step(kt, qt, 1, base, vbase, va0, vb0, va1, vb1, qf,
              KsB, VtB, PlB, acc, mrun, lrun, w, l, q0, vr, vd0);
    __syncthreads();
    if (++kt > qt) break;
  }

  float inv[4];
#pragma unroll
  for (int jj = 0; jj < 4; jj++) inv[jj] = 1.0f / lrun[jj];
  short* obase = ctx + (size_t)(b * SEQ + q0) * D_MODEL + h * 64;
#pragma unroll
  for (int db = 0; db < 4; db++)
#pragma unroll
    for (int jj = 0; jj < 4; jj++)
      obase[(size_t)(l4 * 4 + jj) * D_MODEL + db * 16 + l15] = f2bf(acc[db][jj] * inv[jj]);
}

extern "C" void kernel_launch(void* const* d_in, const int* in_sizes, int n_in,
                              void* d_out, int out_size, void* d_ws, size_t ws_size,
                              hipStream_t stream) {
  (void)in_sizes; (void)n_in; (void)out_size; (void)ws_size;
  const float* x    = (const float*)d_in[0];
  const float* WQ   = (const float*)d_in[1];
  const float* WK   = (const float*)d_in[2];
  const float* WV   = (const float*)d_in[3];
  const float* WO   = (const float*)d_in[4];
  const float* W1   = (const float*)d_in[5];
  const float* b1   = (const float*)d_in[6];
  const float* W2   = (const float*)d_in[7];
  const float* b2   = (const float*)d_in[8];
  const float* ln1w = (const float*)d_in[9];
  const float* ln1b = (const float*)d_in[10];
  const float* ln2w = (const float*)d_in[11];
  const float* ln2b = (const float*)d_in[12];
  float* out = (float*)d_out;

  char* p = (char*)d_ws;
  short* h1    = (short*)p; p += (size_t)ROWS * D_MODEL * 2;        // 8 MB
  short* ctx   = (short*)p; p += (size_t)ROWS * D_MODEL * 2;        // 8 MB
  short* h2    = (short*)p; p += (size_t)ROWS * D_MODEL * 2;        // 8 MB
  short* m1    = (short*)p; p += (size_t)ROWS * DMLP * 2;           // 32 MB
  short* wqkvT = (short*)p; p += (size_t)3 * D_MODEL * D_MODEL * 2; // 6 MB
  short* woT   = (short*)p; p += (size_t)D_MODEL * D_MODEL * 2;     // 2 MB
  short* w1T   = (short*)p; p += (size_t)D_MODEL * DMLP * 2;        // 8 MB
  short* w2T   = (short*)p; p += (size_t)D_MODEL * DMLP * 2;        // 8 MB
  short* qkv   = (short*)p; p += (size_t)ROWS * 3 * D_MODEL * 2;    // 24 MB

  // weight repacks (bf16, B^T layout) via tiled transpose
  transpose_tile<<<dim3(1, 16, 16), 256, 0, stream>>>(WQ, wqkvT,                  1024, 64, D_MODEL * DHEAD);
  transpose_tile<<<dim3(1, 16, 16), 256, 0, stream>>>(WK, wqkvT + 1024 * 1024,    1024, 64, D_MODEL * DHEAD);
  transpose_tile<<<dim3(1, 16, 16), 256, 0, stream>>>(WV, wqkvT + 2 * 1024 * 1024, 1024, 64, D_MODEL * DHEAD);
  transpose_tile<<<dim3(16, 16, 1), 256, 0, stream>>>(WO, woT, 1024, 1024, 0);
  transpose_tile<<<dim3(64, 16, 1), 256, 0, stream>>>(W1, w1T, 1024, 4096, 0);
  transpose_tile<<<dim3(16, 64, 1), 256, 0, stream>>>(W2, w2T, 4096, 1024, 0);

  // LN1
  ln_kernel<<<ROWS, 256, 0, stream>>>(x, ln1w, ln1b, h1);
  // QKV projection: [4096,1024] x [1024,3072] -> bf16 qkv
  gemm_bt<0><<<dim3(3 * D_MODEL / 128, ROWS / 128), 256, 0, stream>>>(
      h1, wqkvT, nullptr, nullptr, nullptr, qkv, ROWS, 3 * D_MODEL, D_MODEL);
  // attention (MFMA flash, pipelined; grid transposed: bh fastest, qt reversed)
  attn_mfma<<<dim3(BATCH * NHEADS, SEQ / 64), 256, 0, stream>>>(qkv, ctx);
  // output projection + residual -> x1 (d_out, f32)
  gemm_bt<1><<<dim3(D_MODEL / 128, ROWS / 128), 256, 0, stream>>>(
      ctx, woT, nullptr, x, out, nullptr, ROWS, D_MODEL, D_MODEL);
  // LN2
  ln_kernel<<<ROWS, 256, 0, stream>>>(out, ln2w, ln2b, h2);
  // MLP fc1 + GELU -> bf16 m1
  gemm_bt<2><<<dim3(DMLP / 128, ROWS / 128), 256, 0, stream>>>(
      h2, w1T, b1, nullptr, nullptr, m1, ROWS, DMLP, D_MODEL);
  // MLP fc2 + bias + residual -> d_out (f32)
  gemm_bt<3><<<dim3(D_MODEL / 128, ROWS / 128), 256, 0, stream>>>(
      m1, w2T, b2, out, out, nullptr, ROWS, D_MODEL, DMLP);
}